// Round 2
// baseline (506.320 us; speedup 1.0000x reference)
//
#include <hip/hip_runtime.h>
#include <stdint.h>

using fx4   = __attribute__((ext_vector_type(4))) float;
using half8 = __attribute__((ext_vector_type(8))) _Float16;

__device__ __forceinline__ ushort f2h(float x) {
  _Float16 h = (_Float16)x;            // v_cvt_f16_f32, RNE
  union { _Float16 hv; ushort u; } v; v.hv = h;
  return v.u;
}

__device__ __forceinline__ void gload_lds16(const ushort* g, ushort* l) {
  __builtin_amdgcn_global_load_lds(
      (__attribute__((address_space(1))) const void*)g,
      (__attribute__((address_space(3))) void*)l, 16, 0, 0);
}

// C[m][n] = sum_k A[m][k] * B[n][k]  (B given transposed, both fp16, fp32 accum)
// flags: bit0 = relu, bit1 = store fp16 (else fp32). bias (fp32, per-col) optional.
__global__ __launch_bounds__(256)
void gemm_bt(const ushort* __restrict__ A, int lda, long long sA,
             const ushort* __restrict__ B, int ldb, long long sB,
             const float* __restrict__ bias,
             void* __restrict__ C, int ldc, long long sC,
             int K, int flags)
{
  __shared__ ushort As[128 * 32];
  __shared__ ushort Bs[128 * 32];
  const int z = blockIdx.z;
  A += (long long)z * sA;
  B += (long long)z * sB;
  const int tid  = threadIdx.x;
  const int lane = tid & 63;
  const int wave = tid >> 6;
  const int wm   = (wave >> 1) * 64;
  const int wn   = (wave & 1) * 64;
  const long long bm = (long long)blockIdx.y * 128;
  const long long bn = (long long)blockIdx.x * 128;

  // staging: 256 threads, each thread = 16B (8 fp16); row = tid/4, kpart = tid%4
  const int srow = tid >> 2;
  const int skq  = (tid & 3) * 8;
  const ushort* a0 = A + (bm + srow) * lda + skq;
  const ushort* a1 = a0 + 64LL * lda;
  const ushort* b0 = B + (bn + srow) * ldb + skq;
  const ushort* b1 = b0 + 64LL * ldb;
  ushort* lA0 = &As[tid * 8];
  ushort* lA1 = &As[2048 + tid * 8];
  ushort* lB0 = &Bs[tid * 8];
  ushort* lB1 = &Bs[2048 + tid * 8];

  fx4 acc[4][4] = {};
  const ushort* ap = &As[(wm + (lane & 15)) * 32 + (lane >> 4) * 8];
  const ushort* bp = &Bs[(wn + (lane & 15)) * 32 + (lane >> 4) * 8];

  for (int k0 = 0; k0 < K; k0 += 32) {
    gload_lds16(a0, lA0);
    gload_lds16(a1, lA1);
    gload_lds16(b0, lB0);
    gload_lds16(b1, lB1);
    a0 += 32; a1 += 32; b0 += 32; b1 += 32;
    __syncthreads();
    half8 af[4], bv[4];
#pragma unroll
    for (int t = 0; t < 4; ++t) {
      af[t] = *(const half8*)(ap + t * 16 * 32);
      bv[t] = *(const half8*)(bp + t * 16 * 32);
    }
#pragma unroll
    for (int i = 0; i < 4; ++i)
#pragma unroll
      for (int j = 0; j < 4; ++j)
        acc[i][j] = __builtin_amdgcn_mfma_f32_16x16x32_f16(af[i], bv[j], acc[i][j], 0, 0, 0);
    __syncthreads();
  }

  const int col0 = (int)bn + wn + (lane & 15);
  const int row0 = (int)bm + wm + ((lane >> 4) << 2);
  float*  Cf = (float*)C + (long long)z * sC;
  ushort* Ch = (ushort*)C + (long long)z * sC;
#pragma unroll
  for (int j = 0; j < 4; ++j) {
    const int col = col0 + j * 16;
    const float bvv = bias ? bias[col] : 0.0f;
#pragma unroll
    for (int i = 0; i < 4; ++i) {
      const long long row = row0 + i * 16;
#pragma unroll
      for (int r = 0; r < 4; ++r) {
        float v = acc[i][j][r] + bvv;
        if (flags & 1) v = fmaxf(v, 0.0f);
        if (flags & 2) Ch[(row + r) * ldc + col] = f2h(v);
        else           Cf[(row + r) * ldc + col] = v;
      }
    }
  }
}

// fp32 [R][C] -> fp16 [C][R]
__global__ __launch_bounds__(256)
void transpose_cast_w(const float* __restrict__ in, ushort* __restrict__ out, int R, int C) {
  __shared__ float tile[32][33];
  const int c0 = blockIdx.x * 32, r0 = blockIdx.y * 32;
  const int tx = threadIdx.x & 31, ty = threadIdx.x >> 5;
#pragma unroll
  for (int i = 0; i < 32; i += 8)
    tile[ty + i][tx] = in[(long long)(r0 + ty + i) * C + (c0 + tx)];
  __syncthreads();
#pragma unroll
  for (int i = 0; i < 32; i += 8)
    out[(long long)(c0 + ty + i) * R + (r0 + tx)] = f2h(tile[tx][ty + i]);
}

// fp16 [z][R][C] -> fp16 [z][C][R]
__global__ __launch_bounds__(256)
void transpose_b16(const ushort* __restrict__ in, ushort* __restrict__ out, int R, int C) {
  __shared__ ushort tile[32][33];
  const long long zo = (long long)blockIdx.z * R * C;
  in += zo; out += zo;
  const int c0 = blockIdx.x * 32, r0 = blockIdx.y * 32;
  const int tx = threadIdx.x & 31, ty = threadIdx.x >> 5;
#pragma unroll
  for (int i = 0; i < 32; i += 8)
    tile[ty + i][tx] = in[(long long)(r0 + ty + i) * C + (c0 + tx)];
  __syncthreads();
#pragma unroll
  for (int i = 0; i < 32; i += 8)
    out[(long long)(c0 + ty + i) * R + (r0 + tx)] = tile[tx][ty + i];
}

__global__ __launch_bounds__(256)
void cast_f32_f16(const float* __restrict__ in, ushort* __restrict__ out) {
  const long long i = ((long long)blockIdx.x * 256 + threadIdx.x) * 4;
  const float4 v = *(const float4*)(in + i);
  ushort4 o;
  o.x = f2h(v.x); o.y = f2h(v.y); o.z = f2h(v.z); o.w = f2h(v.w);
  *(ushort4*)(out + i) = o;
}

// one block per row of 2048 fp32; softmax -> fp16
__global__ __launch_bounds__(256)
void softmax_rows(const float* __restrict__ S, ushort* __restrict__ P) {
  const long long row = blockIdx.x;
  const float* s = S + row * 2048;
  ushort* p = P + row * 2048;
  const int tid = threadIdx.x;
  const int lane = tid & 63, wid = tid >> 6;
  const float4 v0 = *(const float4*)(s + tid * 4);
  const float4 v1 = *(const float4*)(s + 1024 + tid * 4);
  float m = fmaxf(fmaxf(fmaxf(v0.x, v0.y), fmaxf(v0.z, v0.w)),
                  fmaxf(fmaxf(v1.x, v1.y), fmaxf(v1.z, v1.w)));
#pragma unroll
  for (int off = 32; off > 0; off >>= 1) m = fmaxf(m, __shfl_down(m, off, 64));
  __shared__ float redm[4];
  __shared__ float reds[4];
  if (lane == 0) redm[wid] = m;
  __syncthreads();
  m = fmaxf(fmaxf(redm[0], redm[1]), fmaxf(redm[2], redm[3]));
  float e[8];
  e[0] = __expf(v0.x - m); e[1] = __expf(v0.y - m);
  e[2] = __expf(v0.z - m); e[3] = __expf(v0.w - m);
  e[4] = __expf(v1.x - m); e[5] = __expf(v1.y - m);
  e[6] = __expf(v1.z - m); e[7] = __expf(v1.w - m);
  float sum = e[0] + e[1] + e[2] + e[3] + e[4] + e[5] + e[6] + e[7];
#pragma unroll
  for (int off = 32; off > 0; off >>= 1) sum += __shfl_down(sum, off, 64);
  if (lane == 0) reds[wid] = sum;
  __syncthreads();
  sum = reds[0] + reds[1] + reds[2] + reds[3];
  const float inv = 1.0f / sum;
  ushort4 o0, o1;
  o0.x = f2h(e[0] * inv); o0.y = f2h(e[1] * inv);
  o0.z = f2h(e[2] * inv); o0.w = f2h(e[3] * inv);
  o1.x = f2h(e[4] * inv); o1.y = f2h(e[5] * inv);
  o1.z = f2h(e[6] * inv); o1.w = f2h(e[7] * inv);
  *(ushort4*)(p + tid * 4) = o0;
  *(ushort4*)(p + 1024 + tid * 4) = o1;
}

extern "C" void kernel_launch(void* const* d_in, const int* in_sizes, int n_in,
                              void* d_out, int out_size, void* d_ws, size_t ws_size,
                              hipStream_t stream) {
  (void)in_sizes; (void)n_in; (void)out_size; (void)ws_size;
  const float* x   = (const float*)d_in[0];
  const float* We1 = (const float*)d_in[1];
  const float* be1 = (const float*)d_in[2];
  const float* We2 = (const float*)d_in[3];
  const float* be2 = (const float*)d_in[4];
  const float* Wk1 = (const float*)d_in[5];
  const float* bk1 = (const float*)d_in[6];
  const float* Wk2 = (const float*)d_in[7];
  const float* bk2 = (const float*)d_in[8];
  float* out = (float*)d_out;
  char* ws = (char*)d_ws;

  // workspace layout (bytes); P overlaps the early (dead-by-then) region
  ushort* P    = (ushort*)(ws + 0);            // 8*2048*2048 fp16 = 67.1 MB
  ushort* Xb   = (ushort*)(ws + 0);            // 16.78 MB (dead before P written)
  ushort* We1t = (ushort*)(ws + 16777216);
  ushort* We2t = (ushort*)(ws + 17825792);
  ushort* Wk1t = (ushort*)(ws + 18874368);
  ushort* Wk2t = (ushort*)(ws + 19922944);
  ushort* H    = (ushort*)(ws + 20971520);     // 16384x1024 fp16 = 33.55 MB
  ushort* EMB  = (ushort*)(ws + 54525952);     // 16384x512  fp16
  ushort* EMBT = (ushort*)(ws + 71303168);     // 8x512x2048 fp16
  ushort* KQ   = (ushort*)(ws + 88080384);     // 16384x512  fp16
  float*  Sbuf = (float*)(ws + 104857600);     // 2048x2048  fp32 (per-batch reuse)

  // casts
  cast_f32_f16<<<dim3(8192), dim3(256), 0, stream>>>(x, Xb);
  transpose_cast_w<<<dim3(32, 16), dim3(256), 0, stream>>>(We1, We1t, 512, 1024);
  transpose_cast_w<<<dim3(16, 32), dim3(256), 0, stream>>>(We2, We2t, 1024, 512);
  transpose_cast_w<<<dim3(32, 16), dim3(256), 0, stream>>>(Wk1, Wk1t, 512, 1024);
  transpose_cast_w<<<dim3(16, 32), dim3(256), 0, stream>>>(Wk2, Wk2t, 1024, 512);

  // H = relu(x @ We1 + be1)   [16384,1024]
  gemm_bt<<<dim3(8, 128, 1), 256, 0, stream>>>(Xb, 512, 0, We1t, 512, 0, be1,
                                               H, 1024, 0, 512, 1 | 2);
  // EMB = H @ We2 + be2       [16384,512]
  gemm_bt<<<dim3(4, 128, 1), 256, 0, stream>>>(H, 1024, 0, We2t, 1024, 0, be2,
                                               EMB, 512, 0, 1024, 2);
  // EMBT[b][d][m] = EMB[b][m][d]
  transpose_b16<<<dim3(16, 64, 8), 256, 0, stream>>>(EMB, EMBT, 2048, 512);
  // H = relu(x @ Wk1 + bk1)
  gemm_bt<<<dim3(8, 128, 1), 256, 0, stream>>>(Xb, 512, 0, Wk1t, 512, 0, bk1,
                                               H, 1024, 0, 512, 1 | 2);
  // KQ = H @ Wk2 + bk2        [16384,512]; K = [:,0:256], Q = [:,256:512]
  gemm_bt<<<dim3(4, 128, 1), 256, 0, stream>>>(H, 1024, 0, Wk2t, 1024, 0, bk2,
                                               KQ, 512, 0, 1024, 2);

  // attention: per batch scores + softmax (S buffer reused), then batched PV
  for (int b = 0; b < 8; ++b) {
    const ushort* Qb = KQ + (long long)b * 1048576 + 256;
    const ushort* Kb = KQ + (long long)b * 1048576;
    gemm_bt<<<dim3(16, 16, 1), 256, 0, stream>>>(Qb, 512, 0, Kb, 512, 0, nullptr,
                                                 Sbuf, 2048, 0, 256, 0);
    softmax_rows<<<dim3(2048), 256, 0, stream>>>(Sbuf, P + (long long)b * 4194304);
  }
  // out[b][q][d] = sum_k P[b][q][k] * EMBT[b][d][k]   (fp32 out)
  gemm_bt<<<dim3(4, 16, 8), 256, 0, stream>>>(P, 2048, 4194304, EMBT, 2048, 1048576,
                                              nullptr, out, 512, 1048576, 2048, 0);
}

// Round 3
// 397.000 us; speedup vs baseline: 1.2754x; 1.2754x over previous
//
#include <hip/hip_runtime.h>
#include <stdint.h>

using fx4   = __attribute__((ext_vector_type(4))) float;
using half8 = __attribute__((ext_vector_type(8))) _Float16;

__device__ __forceinline__ ushort f2h(float x) {
  _Float16 h = (_Float16)x;
  union { _Float16 hv; ushort u; } v; v.hv = h;
  return v.u;
}

__device__ __forceinline__ void gload_lds16(const ushort* g, ushort* l) {
  __builtin_amdgcn_global_load_lds(
      (__attribute__((address_space(1))) const void*)g,
      (__attribute__((address_space(3))) void*)l, 16, 0, 0);
}

// C[m][n] = sum_k A[m][k] * B[n][k]  (B transposed, fp16 in, fp32 accum)
// flags: 1=relu, 2=store fp16, 4=sumexp->atomicAdd aux[row], 8=softmax store
//        (P=exp(acc-40)/aux[row], fp16), 16=transposed fp16 store (C[col*ldc+row])
__global__ __launch_bounds__(256)
void gemm_bt(const ushort* __restrict__ A, int lda, long long sA,
             const ushort* __restrict__ B, int ldb, long long sB,
             const float* __restrict__ bias,
             void* __restrict__ C, int ldc, long long sC,
             float* __restrict__ aux,
             int K, int flags)
{
  __shared__ ushort As[128 * 32];
  __shared__ ushort Bs[128 * 32];
  const int z = blockIdx.z;
  A += (long long)z * sA;
  B += (long long)z * sB;
  const int tid  = threadIdx.x;
  const int lane = tid & 63;
  const int wave = tid >> 6;
  const int wm   = (wave >> 1) * 64;
  const int wn   = (wave & 1) * 64;
  const long long bm = (long long)blockIdx.y * 128;
  const long long bn = (long long)blockIdx.x * 128;

  const int srow = tid >> 2;
  const int skq  = (tid & 3) * 8;
  const ushort* a0 = A + (bm + srow) * lda + skq;
  const ushort* a1 = a0 + 64LL * lda;
  const ushort* b0 = B + (bn + srow) * ldb + skq;
  const ushort* b1 = b0 + 64LL * ldb;
  ushort* lA0 = &As[tid * 8];
  ushort* lA1 = &As[2048 + tid * 8];
  ushort* lB0 = &Bs[tid * 8];
  ushort* lB1 = &Bs[2048 + tid * 8];

  fx4 acc[4][4] = {};
  const ushort* ap = &As[(wm + (lane & 15)) * 32 + (lane >> 4) * 8];
  const ushort* bp = &Bs[(wn + (lane & 15)) * 32 + (lane >> 4) * 8];

  for (int k0 = 0; k0 < K; k0 += 32) {
    gload_lds16(a0, lA0);
    gload_lds16(a1, lA1);
    gload_lds16(b0, lB0);
    gload_lds16(b1, lB1);
    a0 += 32; a1 += 32; b0 += 32; b1 += 32;
    __syncthreads();
    half8 af[4], bv[4];
#pragma unroll
    for (int t = 0; t < 4; ++t) {
      af[t] = *(const half8*)(ap + t * 16 * 32);
      bv[t] = *(const half8*)(bp + t * 16 * 32);
    }
#pragma unroll
    for (int i = 0; i < 4; ++i)
#pragma unroll
      for (int j = 0; j < 4; ++j)
        acc[i][j] = __builtin_amdgcn_mfma_f32_16x16x32_f16(af[i], bv[j], acc[i][j], 0, 0, 0);
    __syncthreads();
  }

  const int col0 = (int)bn + wn + (lane & 15);
  const int row0 = (int)bm + wm + ((lane >> 4) << 2);

  if (flags & 4) {
    // pass1: l[row] += sum over this block's 64 cols of exp(s-40)
    float* lsum = aux + (long long)z * 2048;
#pragma unroll
    for (int i = 0; i < 4; ++i) {
      fx4 s;
#pragma unroll
      for (int r = 0; r < 4; ++r) {
        float v = 0.0f;
#pragma unroll
        for (int j = 0; j < 4; ++j) v += __expf(acc[i][j][r] - 40.0f);
        s[r] = v;
      }
#pragma unroll
      for (int off = 1; off < 16; off <<= 1) {
#pragma unroll
        for (int r = 0; r < 4; ++r) s[r] += __shfl_xor(s[r], off, 64);
      }
      if ((lane & 15) == 0) {
#pragma unroll
        for (int r = 0; r < 4; ++r)
          atomicAdd(&lsum[row0 + i * 16 + r], s[r]);
      }
    }
    return;
  }

  if (flags & 8) {
    // pass2: P = exp(s-40) / l[row], fp16
    const float* lsum = aux + (long long)z * 2048;
    ushort* Ch = (ushort*)C + (long long)z * sC;
#pragma unroll
    for (int i = 0; i < 4; ++i) {
      const int rowb = row0 + i * 16;
      const float4 lv = *(const float4*)(lsum + rowb);
      const fx4 inv = {1.0f / lv.x, 1.0f / lv.y, 1.0f / lv.z, 1.0f / lv.w};
#pragma unroll
      for (int j = 0; j < 4; ++j) {
        const int col = col0 + j * 16;
#pragma unroll
        for (int r = 0; r < 4; ++r)
          Ch[(long long)(rowb + r) * ldc + col] = f2h(__expf(acc[i][j][r] - 40.0f) * inv[r]);
      }
    }
    return;
  }

  if (flags & 16) {
    // transposed fp16 store: C[col*ldc + row], rows contiguous per lane -> ushort4
    ushort* Ch = (ushort*)C + (long long)z * sC;
#pragma unroll
    for (int j = 0; j < 4; ++j) {
      const int col = col0 + j * 16;
      const float bvv = bias ? bias[col] : 0.0f;
#pragma unroll
      for (int i = 0; i < 4; ++i) {
        const int row = row0 + i * 16;
        ushort4 o;
        o.x = f2h(acc[i][j][0] + bvv);
        o.y = f2h(acc[i][j][1] + bvv);
        o.z = f2h(acc[i][j][2] + bvv);
        o.w = f2h(acc[i][j][3] + bvv);
        *(ushort4*)(Ch + (long long)col * ldc + row) = o;
      }
    }
    return;
  }

  float*  Cf = (float*)C + (long long)z * sC;
  ushort* Ch = (ushort*)C + (long long)z * sC;
#pragma unroll
  for (int j = 0; j < 4; ++j) {
    const int col = col0 + j * 16;
    const float bvv = bias ? bias[col] : 0.0f;
#pragma unroll
    for (int i = 0; i < 4; ++i) {
      const long long row = row0 + i * 16;
#pragma unroll
      for (int r = 0; r < 4; ++r) {
        float v = acc[i][j][r] + bvv;
        if (flags & 1) v = fmaxf(v, 0.0f);
        if (flags & 2) Ch[(row + r) * ldc + col] = f2h(v);
        else           Cf[(row + r) * ldc + col] = v;
      }
    }
  }
}

// fp32 [R][C] -> fp16 [C][R]
__global__ __launch_bounds__(256)
void transpose_cast_w(const float* __restrict__ in, ushort* __restrict__ out, int R, int C) {
  __shared__ float tile[32][33];
  const int c0 = blockIdx.x * 32, r0 = blockIdx.y * 32;
  const int tx = threadIdx.x & 31, ty = threadIdx.x >> 5;
#pragma unroll
  for (int i = 0; i < 32; i += 8)
    tile[ty + i][tx] = in[(long long)(r0 + ty + i) * C + (c0 + tx)];
  __syncthreads();
#pragma unroll
  for (int i = 0; i < 32; i += 8)
    out[(long long)(c0 + ty + i) * R + (r0 + tx)] = f2h(tile[tx][ty + i]);
}

__global__ __launch_bounds__(256)
void cast_f32_f16(const float* __restrict__ in, ushort* __restrict__ out) {
  const long long i = ((long long)blockIdx.x * 256 + threadIdx.x) * 4;
  const float4 v = *(const float4*)(in + i);
  ushort4 o;
  o.x = f2h(v.x); o.y = f2h(v.y); o.z = f2h(v.z); o.w = f2h(v.w);
  *(ushort4*)(out + i) = o;
}

__global__ __launch_bounds__(256)
void concat_bias(const float* __restrict__ b0, const float* __restrict__ b1,
                 float* __restrict__ out) {
  const int i = blockIdx.x * 256 + threadIdx.x;
  out[i] = (i < 1024) ? b0[i] : b1[i - 1024];
}

__global__ __launch_bounds__(256)
void zero_f32(float* __restrict__ p) {
  const int i = (blockIdx.x * 256 + threadIdx.x) * 4;
  *(float4*)(p + i) = float4{0.f, 0.f, 0.f, 0.f};
}

extern "C" void kernel_launch(void* const* d_in, const int* in_sizes, int n_in,
                              void* d_out, int out_size, void* d_ws, size_t ws_size,
                              hipStream_t stream) {
  (void)in_sizes; (void)n_in; (void)out_size; (void)ws_size;
  const float* x   = (const float*)d_in[0];
  const float* We1 = (const float*)d_in[1];
  const float* be1 = (const float*)d_in[2];
  const float* We2 = (const float*)d_in[3];
  const float* be2 = (const float*)d_in[4];
  const float* Wk1 = (const float*)d_in[5];
  const float* bk1 = (const float*)d_in[6];
  const float* Wk2 = (const float*)d_in[7];
  const float* bk2 = (const float*)d_in[8];
  float* out = (float*)d_out;
  char* ws = (char*)d_ws;

  // workspace (bytes) — peak 119.6 MB (< proven 121.6):
  ushort* Xb   = (ushort*)(ws + 0);            // 16.78 MB, dead after gemm1
  ushort* W2c  = (ushort*)(ws + 0);            // 2 MB (We2t|Wk2t), written after gemm1
  ushort* P    = (ushort*)(ws + 0);            // 67.1 MB, written at pass2 (Xb/W2c/H-head dead)
  ushort* H    = (ushort*)(ws + 16777216);     // 16384x2048 fp16 = 67.1 MB
  ushort* EMBT = (ushort*)(ws + 83886080);     // [512][16384] fp16 = 16.78 MB
  ushort* KQ   = (ushort*)(ws + 100663296);    // 16384x512 fp16 = 16.78 MB
  float*  lsum = (float*)(ws + 117440512);     // 16384 fp32
  float*  b1c  = (float*)(ws + 117506048);     // 2048 fp32
  ushort* W1c  = (ushort*)(ws + 117514240);    // 2 MB (We1t|Wk1t)

  // prep
  cast_f32_f16<<<dim3(8192), 256, 0, stream>>>(x, Xb);
  transpose_cast_w<<<dim3(32, 16), 256, 0, stream>>>(We1, W1c, 512, 1024);
  transpose_cast_w<<<dim3(32, 16), 256, 0, stream>>>(Wk1, W1c + 524288, 512, 1024);
  concat_bias<<<dim3(8), 256, 0, stream>>>(be1, bk1, b1c);

  // gemm1: H[16384x2048] = relu(x @ [We1|Wk1] + [be1|bk1])
  gemm_bt<<<dim3(16, 128, 1), 256, 0, stream>>>(Xb, 512, 0, W1c, 512, 0, b1c,
                                                H, 2048, 0, nullptr, 512, 1 | 2);

  // W2 transposes into dead Xb region
  transpose_cast_w<<<dim3(16, 32), 256, 0, stream>>>(We2, W2c, 1024, 512);
  transpose_cast_w<<<dim3(16, 32), 256, 0, stream>>>(Wk2, W2c + 524288, 1024, 512);

  // gemm2a: EMBT[d][tok] = (H[:, :1024] @ We2 + be2)^T  (transposed epilogue store)
  gemm_bt<<<dim3(4, 128, 1), 256, 0, stream>>>(H, 2048, 0, W2c, 1024, 0, be2,
                                               EMBT, 16384, 0, nullptr, 1024, 16);
  // gemm2b: KQ = H[:, 1024:] @ Wk2 + bk2   (K=cols 0:256, Q=cols 256:512)
  gemm_bt<<<dim3(4, 128, 1), 256, 0, stream>>>(H + 1024, 2048, 0, W2c + 524288, 1024, 0, bk2,
                                               KQ, 512, 0, nullptr, 1024, 2);

  // softmax denominators: l[row] = sum_k exp(s-40), batched over all 8 batches
  zero_f32<<<dim3(16), 256, 0, stream>>>(lsum);
  gemm_bt<<<dim3(16, 16, 8), 256, 0, stream>>>(KQ + 256, 512, 1048576, KQ, 512, 1048576,
                                               nullptr, nullptr, 0, 0, lsum, 256, 4);
  // pass2: P = exp(s-40)/l, fp16
  gemm_bt<<<dim3(16, 16, 8), 256, 0, stream>>>(KQ + 256, 512, 1048576, KQ, 512, 1048576,
                                               nullptr, P, 2048, 4194304, lsum, 256, 8);
  // PV: out[b][q][d] = sum_k P[b][q][k] * EMBT[d][b*2048+k]
  gemm_bt<<<dim3(4, 16, 8), 256, 0, stream>>>(P, 2048, 4194304, EMBT, 16384, 2048,
                                              nullptr, out, 512, 1048576, nullptr, 2048, 0);
}

// Round 5
// 378.623 us; speedup vs baseline: 1.3373x; 1.0485x over previous
//
#include <hip/hip_runtime.h>
#include <stdint.h>

using fx4   = __attribute__((ext_vector_type(4))) float;
using half8 = __attribute__((ext_vector_type(8))) _Float16;

__device__ __forceinline__ ushort f2h(float x) {
  _Float16 h = (_Float16)x;
  union { _Float16 hv; ushort u; } v; v.hv = h;
  return v.u;
}

__device__ __forceinline__ void gload_lds16(const ushort* g, ushort* l) {
  __builtin_amdgcn_global_load_lds(
      (__attribute__((address_space(1))) const void*)g,
      (__attribute__((address_space(3))) void*)l, 16, 0, 0);
}

#define MFMA16(a, b, c) __builtin_amdgcn_mfma_f32_16x16x32_f16(a, b, c, 0, 0, 0)

// C[m][n] = sum_k A[m][k] * B[n][k]  (B transposed, fp16 in, fp32 accum)
// flags: 1=relu, 2=store fp16, 16=transposed fp16 store (C[col*ldc+row])
__global__ __launch_bounds__(256)
void gemm_bt(const ushort* __restrict__ A, int lda, long long sA,
             const ushort* __restrict__ B, int ldb, long long sB,
             const float* __restrict__ bias,
             void* __restrict__ C, int ldc, long long sC,
             int K, int flags)
{
  __shared__ ushort As[128 * 32];
  __shared__ ushort Bs[128 * 32];
  const int z = blockIdx.z;
  A += (long long)z * sA;
  B += (long long)z * sB;
  const int tid  = threadIdx.x;
  const int lane = tid & 63;
  const int wave = tid >> 6;
  const int wm   = (wave >> 1) * 64;
  const int wn   = (wave & 1) * 64;
  const long long bm = (long long)blockIdx.y * 128;
  const long long bn = (long long)blockIdx.x * 128;

  const int srow = tid >> 2;
  const int skq  = (tid & 3) * 8;
  const ushort* a0 = A + (bm + srow) * lda + skq;
  const ushort* a1 = a0 + 64LL * lda;
  const ushort* b0 = B + (bn + srow) * ldb + skq;
  const ushort* b1 = b0 + 64LL * ldb;
  ushort* lA0 = &As[tid * 8];
  ushort* lA1 = &As[2048 + tid * 8];
  ushort* lB0 = &Bs[tid * 8];
  ushort* lB1 = &Bs[2048 + tid * 8];

  fx4 acc[4][4] = {};
  const ushort* ap = &As[(wm + (lane & 15)) * 32 + (lane >> 4) * 8];
  const ushort* bp = &Bs[(wn + (lane & 15)) * 32 + (lane >> 4) * 8];

  for (int k0 = 0; k0 < K; k0 += 32) {
    gload_lds16(a0, lA0);
    gload_lds16(a1, lA1);
    gload_lds16(b0, lB0);
    gload_lds16(b1, lB1);
    a0 += 32; a1 += 32; b0 += 32; b1 += 32;
    __syncthreads();
    half8 af[4], bv[4];
#pragma unroll
    for (int t = 0; t < 4; ++t) {
      af[t] = *(const half8*)(ap + t * 16 * 32);
      bv[t] = *(const half8*)(bp + t * 16 * 32);
    }
#pragma unroll
    for (int i = 0; i < 4; ++i)
#pragma unroll
      for (int j = 0; j < 4; ++j)
        acc[i][j] = MFMA16(af[i], bv[j], acc[i][j]);
    __syncthreads();
  }

  const int col0 = (int)bn + wn + (lane & 15);
  const int row0 = (int)bm + wm + ((lane >> 4) << 2);

  if (flags & 16) {
    ushort* Ch = (ushort*)C + (long long)z * sC;
#pragma unroll
    for (int j = 0; j < 4; ++j) {
      const int col = col0 + j * 16;
      const float bvv = bias ? bias[col] : 0.0f;
#pragma unroll
      for (int i = 0; i < 4; ++i) {
        const int row = row0 + i * 16;
        ushort4 o;
        o.x = f2h(acc[i][j][0] + bvv);
        o.y = f2h(acc[i][j][1] + bvv);
        o.z = f2h(acc[i][j][2] + bvv);
        o.w = f2h(acc[i][j][3] + bvv);
        *(ushort4*)(Ch + (long long)col * ldc + row) = o;
      }
    }
    return;
  }

  float*  Cf = (float*)C + (long long)z * sC;
  ushort* Ch = (ushort*)C + (long long)z * sC;
#pragma unroll
  for (int j = 0; j < 4; ++j) {
    const int col = col0 + j * 16;
    const float bvv = bias ? bias[col] : 0.0f;
#pragma unroll
    for (int i = 0; i < 4; ++i) {
      const long long row = row0 + i * 16;
#pragma unroll
      for (int r = 0; r < 4; ++r) {
        float v = acc[i][j][r] + bvv;
        if (flags & 1) v = fmaxf(v, 0.0f);
        if (flags & 2) Ch[(row + r) * ldc + col] = f2h(v);
        else           Cf[(row + r) * ldc + col] = v;
      }
    }
  }
}

// Fused attention: per block = (batch, 32-row Q-tile). Two in-block passes:
//  A: l[row] = sum_k exp(s-40) (fp32), B: O += (exp(s-40)/l as fp16) @ V.
// LDS: Qs 16KB | U 64KB (Ks panels / Ps 8KB + Vs 32KB) = 80KB -> 2 blocks/CU.
__global__ __launch_bounds__(256, 2)
void attn_fused(const ushort* __restrict__ KQ, const ushort* __restrict__ EMBT,
                float* __restrict__ out)
{
  __shared__ ushort smem[40960];     // 80 KB exactly
  ushort* const Qs = smem;           // 8 panels [32][32]
  ushort* const U  = smem + 8192;    // 32768 ushorts

  const int tid  = threadIdx.x;
  const int lane = tid & 63;
  const int w    = tid >> 6;
  const int c    = lane & 15;
  const int q4   = lane >> 4;
  const int z    = blockIdx.x;                  // batch -> XCD locality
  const long long tb = (long long)z * 2048;
  const int q0   = blockIdx.y * 32;

  // stage Q-tile 32x256 once: panels [dchunk][row][32]
#pragma unroll
  for (int p = 0; p < 4; ++p) {
    const int u = p * 256 + tid;
    const int panel = u >> 7, row = (u & 127) >> 2, kg = (u & 3) * 8;
    gload_lds16(KQ + (tb + q0 + row) * 512 + 256 + panel * 32 + kg, Qs + u * 8);
  }

  float lp[2][4] = {};
  // ---------- pass A: l ----------
  for (int t0 = 0; t0 < 2048; t0 += 128) {
#pragma unroll
    for (int p = 0; p < 16; ++p) {
      const int u = p * 256 + tid;
      const int panel = u >> 9, row = (u & 511) >> 2, kg = (u & 3) * 8;
      gload_lds16(KQ + (tb + t0 + row) * 512 + panel * 32 + kg, U + u * 8);
    }
    __syncthreads();
    fx4 s[2][2] = {};
#pragma unroll
    for (int dc = 0; dc < 8; ++dc) {
      const half8 a0 = *(const half8*)(Qs + dc * 1024 + c * 32 + q4 * 8);
      const half8 a1 = *(const half8*)(Qs + dc * 1024 + (16 + c) * 32 + q4 * 8);
      const half8 b0 = *(const half8*)(U + dc * 4096 + (w * 32 + c) * 32 + q4 * 8);
      const half8 b1 = *(const half8*)(U + dc * 4096 + (w * 32 + 16 + c) * 32 + q4 * 8);
      s[0][0] = MFMA16(a0, b0, s[0][0]); s[0][1] = MFMA16(a0, b1, s[0][1]);
      s[1][0] = MFMA16(a1, b0, s[1][0]); s[1][1] = MFMA16(a1, b1, s[1][1]);
    }
#pragma unroll
    for (int i = 0; i < 2; ++i)
#pragma unroll
      for (int r = 0; r < 4; ++r)
        lp[i][r] += __expf(s[i][0][r] - 40.0f) + __expf(s[i][1][r] - 40.0f);
    __syncthreads();
  }
  // reduce l across 16-lane col groups, then across waves via LDS
#pragma unroll
  for (int i = 0; i < 2; ++i)
#pragma unroll
    for (int r = 0; r < 4; ++r) {
      float v = lp[i][r];
      v += __shfl_xor(v, 1, 64); v += __shfl_xor(v, 2, 64);
      v += __shfl_xor(v, 4, 64); v += __shfl_xor(v, 8, 64);
      lp[i][r] = v;
    }
  float* l_lds = (float*)U;   // [4][32], U dead between passes
  if (c == 0) {
#pragma unroll
    for (int i = 0; i < 2; ++i)
#pragma unroll
      for (int r = 0; r < 4; ++r)
        l_lds[w * 32 + i * 16 + q4 * 4 + r] = lp[i][r];
  }
  __syncthreads();
  float linv[2][4];
#pragma unroll
  for (int i = 0; i < 2; ++i)
#pragma unroll
    for (int r = 0; r < 4; ++r) {
      const int row = i * 16 + q4 * 4 + r;
      linv[i][r] = 1.0f / (l_lds[row] + l_lds[32 + row] + l_lds[64 + row] + l_lds[96 + row]);
    }
  __syncthreads();

  // ---------- pass B: O = P @ V ----------
  fx4 o[2][8] = {};
  for (int t0 = 0; t0 < 2048; t0 += 128) {
#pragma unroll
    for (int p = 0; p < 16; ++p) {
      const int u = p * 256 + tid;
      const int panel = u >> 9, row = (u & 511) >> 2, kg = (u & 3) * 8;
      gload_lds16(KQ + (tb + t0 + row) * 512 + panel * 32 + kg, U + u * 8);
    }
    __syncthreads();
    fx4 s[2][2] = {};
#pragma unroll
    for (int dc = 0; dc < 8; ++dc) {
      const half8 a0 = *(const half8*)(Qs + dc * 1024 + c * 32 + q4 * 8);
      const half8 a1 = *(const half8*)(Qs + dc * 1024 + (16 + c) * 32 + q4 * 8);
      const half8 b0 = *(const half8*)(U + dc * 4096 + (w * 32 + c) * 32 + q4 * 8);
      const half8 b1 = *(const half8*)(U + dc * 4096 + (w * 32 + 16 + c) * 32 + q4 * 8);
      s[0][0] = MFMA16(a0, b0, s[0][0]); s[0][1] = MFMA16(a0, b1, s[0][1]);
      s[1][0] = MFMA16(a1, b0, s[1][0]); s[1][1] = MFMA16(a1, b1, s[1][1]);
    }
    __syncthreads();            // all waves done reading Ks before Ps overwrite
    ushort* Ps = U;             // 4 panels [32][32]; wave w owns panel w
#pragma unroll
    for (int i = 0; i < 2; ++i)
#pragma unroll
      for (int j = 0; j < 2; ++j)
#pragma unroll
        for (int r = 0; r < 4; ++r)
          Ps[w * 1024 + (i * 16 + q4 * 4 + r) * 32 + j * 16 + c] =
              f2h(__expf(s[i][j][r] - 40.0f) * linv[i][r]);
    __syncthreads();
    ushort* Vs = U + 4096;      // [512][32]
    for (int kc = 0; kc < 4; ++kc) {
#pragma unroll
      for (int p = 0; p < 8; ++p) {
        const int u = p * 256 + tid;
        const int d = u >> 2, tg = (u & 3) * 8;
        gload_lds16(EMBT + (long long)d * 16384 + tb + t0 + kc * 32 + tg, Vs + u * 8);
      }
      __syncthreads();
      const half8 pa0 = *(const half8*)(Ps + kc * 1024 + c * 32 + q4 * 8);
      const half8 pa1 = *(const half8*)(Ps + kc * 1024 + (16 + c) * 32 + q4 * 8);
#pragma unroll
      for (int j = 0; j < 8; ++j) {
        const half8 vb = *(const half8*)(Vs + (w * 128 + j * 16 + c) * 32 + q4 * 8);
        o[0][j] = MFMA16(pa0, vb, o[0][j]);
        o[1][j] = MFMA16(pa1, vb, o[1][j]);
      }
      __syncthreads();
    }
  }

  float* ob = out + (tb + q0) * 512;
#pragma unroll
  for (int i = 0; i < 2; ++i)
#pragma unroll
    for (int r = 0; r < 4; ++r) {
      const int row = i * 16 + q4 * 4 + r;
#pragma unroll
      for (int j = 0; j < 8; ++j)
        ob[(long long)row * 512 + w * 128 + j * 16 + c] = o[i][j][r];
    }
}

// fp32 [R][C] -> fp16 [C][R]
__global__ __launch_bounds__(256)
void transpose_cast_w(const float* __restrict__ in, ushort* __restrict__ out, int R, int C) {
  __shared__ float tile[32][33];
  const int c0 = blockIdx.x * 32, r0 = blockIdx.y * 32;
  const int tx = threadIdx.x & 31, ty = threadIdx.x >> 5;
#pragma unroll
  for (int i = 0; i < 32; i += 8)
    tile[ty + i][tx] = in[(long long)(r0 + ty + i) * C + (c0 + tx)];
  __syncthreads();
#pragma unroll
  for (int i = 0; i < 32; i += 8)
    out[(long long)(c0 + ty + i) * R + (r0 + tx)] = f2h(tile[tx][ty + i]);
}

__global__ __launch_bounds__(256)
void cast_f32_f16(const float* __restrict__ in, ushort* __restrict__ out) {
  const long long i = ((long long)blockIdx.x * 256 + threadIdx.x) * 4;
  const float4 v = *(const float4*)(in + i);
  ushort4 o;
  o.x = f2h(v.x); o.y = f2h(v.y); o.z = f2h(v.z); o.w = f2h(v.w);
  *(ushort4*)(out + i) = o;
}

__global__ __launch_bounds__(256)
void concat_bias(const float* __restrict__ b0, const float* __restrict__ b1,
                 float* __restrict__ out) {
  const int i = blockIdx.x * 256 + threadIdx.x;
  out[i] = (i < 1024) ? b0[i] : b1[i - 1024];
}

extern "C" void kernel_launch(void* const* d_in, const int* in_sizes, int n_in,
                              void* d_out, int out_size, void* d_ws, size_t ws_size,
                              hipStream_t stream) {
  (void)in_sizes; (void)n_in; (void)out_size; (void)ws_size;
  const float* x   = (const float*)d_in[0];
  const float* We1 = (const float*)d_in[1];
  const float* be1 = (const float*)d_in[2];
  const float* We2 = (const float*)d_in[3];
  const float* be2 = (const float*)d_in[4];
  const float* Wk1 = (const float*)d_in[5];
  const float* bk1 = (const float*)d_in[6];
  const float* Wk2 = (const float*)d_in[7];
  const float* bk2 = (const float*)d_in[8];
  float* out = (float*)d_out;
  char* ws = (char*)d_ws;

  ushort* Xb   = (ushort*)(ws + 0);            // 16.78 MB, dead after gemm1
  ushort* W2c  = (ushort*)(ws + 0);            // 2 MB, written after gemm1
  ushort* H    = (ushort*)(ws + 16777216);     // 16384x2048 fp16 = 67.1 MB
  ushort* EMBT = (ushort*)(ws + 83886080);     // [512][16384] fp16 = 16.78 MB
  ushort* KQ   = (ushort*)(ws + 100663296);    // 16384x512 fp16 = 16.78 MB
  float*  b1c  = (float*)(ws + 117440512);     // 2048 fp32
  ushort* W1c  = (ushort*)(ws + 117448704);    // 2 MB

  cast_f32_f16<<<dim3(8192), 256, 0, stream>>>(x, Xb);
  transpose_cast_w<<<dim3(32, 16), 256, 0, stream>>>(We1, W1c, 512, 1024);
  transpose_cast_w<<<dim3(32, 16), 256, 0, stream>>>(Wk1, W1c + 524288, 512, 1024);
  concat_bias<<<dim3(8), 256, 0, stream>>>(be1, bk1, b1c);

  // H = relu(x @ [We1|Wk1] + [be1|bk1])   [16384,2048]
  gemm_bt<<<dim3(16, 128, 1), 256, 0, stream>>>(Xb, 512, 0, W1c, 512, 0, b1c,
                                                H, 2048, 0, 512, 1 | 2);

  transpose_cast_w<<<dim3(16, 32), 256, 0, stream>>>(We2, W2c, 1024, 512);
  transpose_cast_w<<<dim3(16, 32), 256, 0, stream>>>(Wk2, W2c + 524288, 1024, 512);

  // EMBT[d][tok] = (H[:, :1024] @ We2 + be2)^T
  gemm_bt<<<dim3(4, 128, 1), 256, 0, stream>>>(H, 2048, 0, W2c, 1024, 0, be2,
                                               EMBT, 16384, 0, 1024, 16);
  // KQ = H[:, 1024:] @ Wk2 + bk2
  gemm_bt<<<dim3(4, 128, 1), 256, 0, stream>>>(H + 1024, 2048, 0, W2c + 524288, 1024, 0, bk2,
                                               KQ, 512, 0, 1024, 2);

  // fused attention: grid x=batch (XCD-local), y=Q-tile
  attn_fused<<<dim3(8, 64), 256, 0, stream>>>(KQ, EMBT, out);
}